// Round 2
// baseline (9471.113 us; speedup 1.0000x reference)
//
#include <hip/hip_runtime.h>

// LSTM T=4096, IN=32, H=512, OUT=32, 3 layers + projection.
// R15 = R10/R13 communication structure (full revert of R14 mailboxes)
//       + LDS-atomic partial accumulation to shorten the serial tail.
//   R14 post-mortem: per-consumer mailboxes regressed +21%. WRITE_SIZE
//   49MB -> 1.6GB showed the 8-wave redundant publish octupled critical-path
//   write-through volume; fan-out serialization was NOT the missing term.
//   "publish = ONE wave, ONE 128B line" is confirmed load-bearing (R6+R14).
//   R15 theory: step ~3640 cyc = publish->observe (~1400, irreducible per
//   R12/R14) + own-dot issue (~500) + tail (~400) + barrier/misc. The tail
//   (16 ds_read + 15 adds + 4 bpermute before gates) is the only safe
//   remaining lever: replace with ds_add_f32 partial accumulation into a
//   bias-preloaded part2[2][64]; post-barrier tail = 4 broadcast ds_read
//   (gate totals directly) + gates + publish. Re-arm ordering: per-wave DS
//   in-order + wave_barrier() fence; cross-wave via the step barrier chain.
// Protocol invariants (R3-R14):
//   - packed u64 {seq-tag:32 | value:32}: the flag IS the data;
//   - relaxed agent-scope atomics only, NO cache-wide fences;
//   - <=64 weight floats/lane, loop-constant indexing;
//   - publish = ONE wave storing ONE full 128B line;
//   - per-wave poll straight into VGPRs, readlane-broadcast dot;
//   - ONE s_barrier per step, part buffers double-buffered.

#define T_SEQ 4096
#define HDIM  512
#define NWG_L 32
#define NTH   1024

typedef unsigned long long u64;

__device__ __forceinline__ u64 cohLoad(const u64* p) {
    return __hip_atomic_load(p, __ATOMIC_RELAXED, __HIP_MEMORY_SCOPE_AGENT);
}
__device__ __forceinline__ void cohStore(u64* p, u64 v) {
    __hip_atomic_store(p, v, __ATOMIC_RELAXED, __HIP_MEMORY_SCOPE_AGENT);
}
__device__ __forceinline__ float fsigmoid(float x) {
    return __builtin_amdgcn_rcpf(1.f + __expf(-x));
}
__device__ __forceinline__ float ftanh(float x) {
    float e = __expf(2.f * fabsf(x));           // +inf ok -> t = 1
    float t = 1.f - 2.f * __builtin_amdgcn_rcpf(e + 1.f);
    return copysignf(t, x);
}
__device__ __forceinline__ float bcast(float v, int k) {
    return __uint_as_float(__builtin_amdgcn_readlane(__float_as_uint(v), k));
}

// ---------------------------------------------------------------------------
// Tiled fp32 GEMM (final projection): C[M][N] = A[M][K] * B[N][K]^T + bias[n]
// ---------------------------------------------------------------------------
template <int BM, int BN, int BK>
__global__ __launch_bounds__(256)
void gemm_abt(const float* __restrict__ A, const float* __restrict__ B,
              const float* __restrict__ bias1,
              float* __restrict__ C, int M, int N, int K) {
    constexpr int NTX = BN / 4;
    constexpr int NTY = 256 / NTX;
    constexpr int TM  = BM / NTY;
    __shared__ float As[BM][BK + 1];
    __shared__ float Bs[BN][BK + 1];

    const int tid = threadIdx.x;
    const int tx = tid % NTX;
    const int ty = tid / NTX;
    const int m0 = blockIdx.y * BM;
    const int n0 = blockIdx.x * BN;

    float acc[TM][4];
    #pragma unroll
    for (int i = 0; i < TM; ++i)
        #pragma unroll
        for (int j = 0; j < 4; ++j) acc[i][j] = 0.f;

    for (int k0 = 0; k0 < K; k0 += BK) {
        constexpr int AV = BM * BK / 4;
        #pragma unroll
        for (int i = tid; i < AV; i += 256) {
            int r = i / (BK / 4), c4 = i % (BK / 4);
            float4 v = *(const float4*)(A + (size_t)(m0 + r) * K + k0 + c4 * 4);
            As[r][c4 * 4 + 0] = v.x; As[r][c4 * 4 + 1] = v.y;
            As[r][c4 * 4 + 2] = v.z; As[r][c4 * 4 + 3] = v.w;
        }
        constexpr int BV = BN * BK / 4;
        #pragma unroll
        for (int i = tid; i < BV; i += 256) {
            int r = i / (BK / 4), c4 = i % (BK / 4);
            float4 v = *(const float4*)(B + (size_t)(n0 + r) * K + k0 + c4 * 4);
            Bs[r][c4 * 4 + 0] = v.x; Bs[r][c4 * 4 + 1] = v.y;
            Bs[r][c4 * 4 + 2] = v.z; Bs[r][c4 * 4 + 3] = v.w;
        }
        __syncthreads();
        #pragma unroll
        for (int kk = 0; kk < BK; ++kk) {
            float a[TM], b[4];
            #pragma unroll
            for (int i = 0; i < TM; ++i) a[i] = As[ty * TM + i][kk];
            #pragma unroll
            for (int j = 0; j < 4; ++j) b[j] = Bs[tx * 4 + j][kk];
            #pragma unroll
            for (int i = 0; i < TM; ++i)
                #pragma unroll
                for (int j = 0; j < 4; ++j) acc[i][j] += a[i] * b[j];
        }
        __syncthreads();
    }

    #pragma unroll
    for (int j = 0; j < 4; ++j) {
        float bv = bias1 ? bias1[n0 + tx * 4 + j] : 0.f;
        #pragma unroll
        for (int i = 0; i < TM; ++i) acc[i][j] += bv;
    }
    #pragma unroll
    for (int i = 0; i < TM; ++i) {
        int m = m0 + ty * TM + i;
        float4 v = make_float4(acc[i][0], acc[i][1], acc[i][2], acc[i][3]);
        *(float4*)(C + (size_t)m * N + n0 + tx * 4) = v;
    }
}

// ---------------------------------------------------------------------------
__global__ void unpack_h(const u64* __restrict__ hp, float* __restrict__ out,
                         int n) {
    int i = blockIdx.x * blockDim.x + threadIdx.x;
    if (i < n) out[i] = __uint_as_float((unsigned)hp[i]);
}

// ---------------------------------------------------------------------------
// 32 WGs/layer x 1024 thr (16 waves). Lane = row (gate*16 + col_local).
// Layers 1/2: wave wv owns k-chunk [wv*64,+64) of concat [prev-h; own-h]:
//   wv<8 -> prev-h / Wih, wv>=8 -> own-h / Whh. Lane polls one element into
//   a VGPR; dot = 64x readlane-broadcast + fmac against w[64].
// Layer 0: wave wv owns own-h k [wv*32,+32) (lanes 0-31 poll); wave 15 also
//   handles x (32 floats of seq, weights in w[32..63]).
// Partials: ds_add_f32 into part2[pb][row] (pre-loaded with bias); wave 0's
//   post-barrier tail = 4 broadcast ds_read (gate totals) + gates + publish.
// ---------------------------------------------------------------------------
__global__ __launch_bounds__(NTH, 4)
void lstm_fused(const float* __restrict__ seq,
                const float* __restrict__ Wih1, const float* __restrict__ Whh1,
                const float* __restrict__ bih1, const float* __restrict__ bhh1,
                const float* __restrict__ Wih2, const float* __restrict__ Whh2,
                const float* __restrict__ bih2, const float* __restrict__ bhh2,
                const float* __restrict__ Wih3, const float* __restrict__ Whh3,
                const float* __restrict__ bih3, const float* __restrict__ bhh3,
                u64* __restrict__ hp) {
    __shared__ float part2[2][64];      // [pb][row], holds bias + partials

    const int blk   = blockIdx.x;
    const int layer = blk >> 5;
    const int g     = blk & 31;
    const int tid   = threadIdx.x;
    const int wv    = tid >> 6;          // 0..15
    const int lane  = tid & 63;          // = row (gate*16 + col_local)
    const int grow  = (lane >> 4) * HDIM + g * 16 + (lane & 15);

    const float* Wih = layer == 0 ? Wih1 : (layer == 1 ? Wih2 : Wih3);
    const float* Whh = layer == 0 ? Whh1 : (layer == 1 ? Whh2 : Whh3);
    const float* bih = layer == 0 ? bih1 : (layer == 1 ? bih2 : bih3);
    const float* bhh = layer == 0 ? bhh1 : (layer == 1 ? bhh2 : bhh3);

    // ---- 64 weight floats/lane (loop-constant indexing only) ----
    float w[64];
    #pragma unroll
    for (int m = 0; m < 64; ++m) w[m] = 0.f;
    if (layer == 0) {
        const float* wp = Whh + (size_t)grow * HDIM + wv * 32;
        #pragma unroll
        for (int i = 0; i < 8; ++i) {
            float4 v = ((const float4*)wp)[i];
            w[4*i+0]=v.x; w[4*i+1]=v.y; w[4*i+2]=v.z; w[4*i+3]=v.w;
        }
        if (wv == 15) {   // x weights -> w[32..63]
            const float* xp = Wih + (size_t)grow * 32;
            #pragma unroll
            for (int i = 0; i < 8; ++i) {
                float4 v = ((const float4*)xp)[i];
                w[32+4*i+0]=v.x; w[32+4*i+1]=v.y;
                w[32+4*i+2]=v.z; w[32+4*i+3]=v.w;
            }
        }
    } else {
        const float* wp = (wv < 8)
            ? Wih + (size_t)grow * HDIM + wv * 64
            : Whh + (size_t)grow * HDIM + (wv - 8) * 64;
        #pragma unroll
        for (int i = 0; i < 16; ++i) {
            float4 v = ((const float4*)wp)[i];
            w[4*i+0]=v.x; w[4*i+1]=v.y; w[4*i+2]=v.z; w[4*i+3]=v.w;
        }
    }
    #pragma unroll
    for (int m = 0; m < 64; ++m) asm volatile("" : "+v"(w[m]));

    const float brow = bih[grow] + bhh[grow];

    // Pre-arm both partial buffers with the bias (added exactly once/step).
    if (wv == 0) {
        part2[0][lane] = brow;
        part2[1][lane] = brow;
    }
    __syncthreads();

    u64*       hpOwn  = hp + (size_t)layer * T_SEQ * HDIM;
    const u64* hpPrev = hp + (size_t)(layer > 0 ? layer - 1 : 0) * T_SEQ * HDIM;

    float c = 0.f;   // cell state (wave 0, lanes 0..15)

    for (unsigned t = 0; t < T_SEQ; ++t) {
        const int pb = t & 1;

        // ---- per-wave poll: chunk element straight into a VGPR ----
        float hval = 0.f;
        float xval = 0.f;
        if (layer == 0) {
            if (lane < 32 && t > 0) {
                const u64* ph = hpOwn + (size_t)(t - 1) * HDIM + wv * 32 + lane;
                u64 v;
                do { v = cohLoad(ph); } while ((unsigned)(v >> 32) != t);
                hval = __uint_as_float((unsigned)v);
            }
            if (wv == 15 && lane < 32)
                xval = seq[(size_t)t * 32 + lane];
        } else {
            if (wv < 8) {                        // prev-layer h[t], tag t+1
                const u64* px = hpPrev + (size_t)t * HDIM + wv * 64 + lane;
                u64 v;
                do { v = cohLoad(px); } while ((unsigned)(v >> 32) != t + 1u);
                hval = __uint_as_float((unsigned)v);
            } else if (t > 0) {                  // own h[t-1], tag t
                const u64* ph = hpOwn + (size_t)(t - 1) * HDIM
                              + (wv - 8) * 64 + lane;
                u64 v;
                do { v = cohLoad(ph); } while ((unsigned)(v >> 32) != t);
                hval = __uint_as_float((unsigned)v);
            }
        }

        // ---- dot: readlane broadcast + fmac, NO LDS ----
        float pe = 0.f, po = 0.f;
        if (layer == 0) {
            #pragma unroll
            for (int k = 0; k < 32; k += 2) {
                pe = fmaf(bcast(hval, k),     w[k],     pe);
                po = fmaf(bcast(hval, k + 1), w[k + 1], po);
            }
            if (wv == 15) {
                #pragma unroll
                for (int k = 0; k < 32; k += 2) {
                    pe = fmaf(bcast(xval, k),     w[32 + k],     pe);
                    po = fmaf(bcast(xval, k + 1), w[32 + k + 1], po);
                }
            }
        } else {
            #pragma unroll
            for (int k = 0; k < 64; k += 2) {
                pe = fmaf(bcast(hval, k),     w[k],     pe);
                po = fmaf(bcast(hval, k + 1), w[k + 1], po);
            }
        }
        // HW LDS float atomic (ds_add_f32): one DS op per wave, issued
        // pre-barrier; off critical path except for the last-arriving wave.
        unsafeAtomicAdd(&part2[pb][lane], pe + po);
        __syncthreads();

        // ---- wave 0: 4 broadcast reads (totals incl. bias), gates, publish --
        if (wv == 0) {
            const int c16 = lane & 15;
            float ai = part2[pb][c16 +  0];
            float af = part2[pb][c16 + 16];
            float ag = part2[pb][c16 + 32];
            float ao = part2[pb][c16 + 48];
            __builtin_amdgcn_wave_barrier();     // keep re-arm below the reads
            part2[pb][lane] = brow;              // re-arm pb for step t+2:
            // per-wave DS ops process in order (reads above land first);
            // other waves touch pb at t+2 only after barrier(t+1), which
            // wave 0 reaches only after this store. No timing assumptions.
            if (lane < 16) {
                float iv = fsigmoid(ai);
                float fv = fsigmoid(af);
                float gv = ftanh(ag);
                float ov = fsigmoid(ao);
                c = fv * c + iv * gv;
                float h = ov * ftanh(c);
                u64 pkt = (u64)__float_as_uint(h) | ((u64)(t + 1u) << 32);
                cohStore(hpOwn + (size_t)t * HDIM + g * 16 + lane, pkt);
            }
        }
        // Other waves roll straight into polling t+1 (no pre-dot barrier:
        // each wave consumes only its own polled registers). part2[] is
        // double-buffered; atomics to part2[pb] recur only at t+2, after
        // barrier(t+1), which wave 0 reaches only after its tail(t).
    }
}

// ---------------------------------------------------------------------------
extern "C" void kernel_launch(void* const* d_in, const int* in_sizes, int n_in,
                              void* d_out, int out_size, void* d_ws, size_t ws_size,
                              hipStream_t stream) {
    const float* seq   = (const float*)d_in[0];
    const float* W_ih1 = (const float*)d_in[1];
    const float* W_hh1 = (const float*)d_in[2];
    const float* b_ih1 = (const float*)d_in[3];
    const float* b_hh1 = (const float*)d_in[4];
    const float* W_ih2 = (const float*)d_in[5];
    const float* W_hh2 = (const float*)d_in[6];
    const float* b_ih2 = (const float*)d_in[7];
    const float* b_hh2 = (const float*)d_in[8];
    const float* W_ih3 = (const float*)d_in[9];
    const float* W_hh3 = (const float*)d_in[10];
    const float* b_ih3 = (const float*)d_in[11];
    const float* b_hh3 = (const float*)d_in[12];
    const float* W_out = (const float*)d_in[13];
    const float* b_out = (const float*)d_in[14];
    float* out = (float*)d_out;

    // Workspace: hp[3][T][512] packed u64 (50.3MB); hs2 floats reuse the
    // dead layer-0 packed region after the recurrence.
    u64*   hp   = (u64*)d_ws;
    float* hs2f = (float*)d_ws;
    const u64* hp2 = hp + (size_t)2 * T_SEQ * HDIM;

    hipMemsetAsync(hp, 0, (size_t)3 * T_SEQ * HDIM * sizeof(u64), stream);

    lstm_fused<<<3 * NWG_L, NTH, 0, stream>>>(
        seq, W_ih1, W_hh1, b_ih1, b_hh1, W_ih2, W_hh2, b_ih2, b_hh2,
        W_ih3, W_hh3, b_ih3, b_hh3, hp);

    const int n = T_SEQ * HDIM;
    unpack_h<<<(n + 255) / 256, 256, 0, stream>>>(hp2, hs2f, n);

    gemm_abt<64, 32, 32><<<dim3(1, T_SEQ / 64), 256, 0, stream>>>(
        hs2f, W_out, b_out, out, T_SEQ, 32, HDIM);
}

// Round 3
// 6269.733 us; speedup vs baseline: 1.5106x; 1.5106x over previous
//
#include <hip/hip_runtime.h>

// LSTM T=4096, IN=32, H=512, OUT=32, 3 layers + projection.
// R16 = R10/R13 structure (full revert of R15 LDS-atomic reduce)
//       + layer-0 x-dot spread across all 16 waves (lead-cascade unlock).
//   R15 post-mortem: ds_add_f32 same-address atomics across 16 waves
//   serialize at the LDS atomic unit -> +51%. With R11 (+21%) and R15,
//   the R10 tail/sync structure is confirmed a sharp local optimum.
//   R16 theory: per-step cycle = store-visibility + poll-quantization
//   (~1000) + SIMD issue burst (16 waves x 128 insts x 2cy / 4 SIMD =
//   ~1024, own+prev dots colliding in the zero-lead equilibrium) +
//   barrier + tail (~550) + 32-publisher max-coupling. hp keeps FULL
//   history, so a faster layer runs ahead unboundedly; its successor's
//   prev-polls then hit instantly and the prev-dot overlaps the own-poll
//   idle window (burst halves). The cascade is blocked ONLY by L0's
//   wave-15 imbalance (it alone carries the 32-wide x-dot: +256 cyc on
//   its SIMD every step => L0 period ~= L1/2 period => no lead).
//   Change: all 16 L0 waves take 2 x-elements each (idle lanes 32-33
//   load them; weights in w[32..33]; +4 insts/wave). Protocol untouched.
// Protocol invariants (R3-R15):
//   - packed u64 {seq-tag:32 | value:32}: the flag IS the data;
//   - relaxed agent-scope atomics only, NO cache-wide fences;
//   - <=64 weight floats/lane, loop-constant indexing;
//   - publish = ONE wave storing ONE full 128B line;
//   - per-wave poll straight into VGPRs, readlane-broadcast dot;
//   - ONE s_barrier per step, part[] double-buffered;
//   - partial reduction = wave-0 LDS reads (R11/R15: alternatives lose).

#define T_SEQ 4096
#define HDIM  512
#define NWG_L 32
#define NTH   1024

typedef unsigned long long u64;

__device__ __forceinline__ u64 cohLoad(const u64* p) {
    return __hip_atomic_load(p, __ATOMIC_RELAXED, __HIP_MEMORY_SCOPE_AGENT);
}
__device__ __forceinline__ void cohStore(u64* p, u64 v) {
    __hip_atomic_store(p, v, __ATOMIC_RELAXED, __HIP_MEMORY_SCOPE_AGENT);
}
__device__ __forceinline__ float fsigmoid(float x) {
    return __builtin_amdgcn_rcpf(1.f + __expf(-x));
}
__device__ __forceinline__ float ftanh(float x) {
    float e = __expf(2.f * fabsf(x));           // +inf ok -> t = 1
    float t = 1.f - 2.f * __builtin_amdgcn_rcpf(e + 1.f);
    return copysignf(t, x);
}
__device__ __forceinline__ float bcast(float v, int k) {
    return __uint_as_float(__builtin_amdgcn_readlane(__float_as_uint(v), k));
}

// ---------------------------------------------------------------------------
// Tiled fp32 GEMM (final projection): C[M][N] = A[M][K] * B[N][K]^T + bias[n]
// ---------------------------------------------------------------------------
template <int BM, int BN, int BK>
__global__ __launch_bounds__(256)
void gemm_abt(const float* __restrict__ A, const float* __restrict__ B,
              const float* __restrict__ bias1,
              float* __restrict__ C, int M, int N, int K) {
    constexpr int NTX = BN / 4;
    constexpr int NTY = 256 / NTX;
    constexpr int TM  = BM / NTY;
    __shared__ float As[BM][BK + 1];
    __shared__ float Bs[BN][BK + 1];

    const int tid = threadIdx.x;
    const int tx = tid % NTX;
    const int ty = tid / NTX;
    const int m0 = blockIdx.y * BM;
    const int n0 = blockIdx.x * BN;

    float acc[TM][4];
    #pragma unroll
    for (int i = 0; i < TM; ++i)
        #pragma unroll
        for (int j = 0; j < 4; ++j) acc[i][j] = 0.f;

    for (int k0 = 0; k0 < K; k0 += BK) {
        constexpr int AV = BM * BK / 4;
        #pragma unroll
        for (int i = tid; i < AV; i += 256) {
            int r = i / (BK / 4), c4 = i % (BK / 4);
            float4 v = *(const float4*)(A + (size_t)(m0 + r) * K + k0 + c4 * 4);
            As[r][c4 * 4 + 0] = v.x; As[r][c4 * 4 + 1] = v.y;
            As[r][c4 * 4 + 2] = v.z; As[r][c4 * 4 + 3] = v.w;
        }
        constexpr int BV = BN * BK / 4;
        #pragma unroll
        for (int i = tid; i < BV; i += 256) {
            int r = i / (BK / 4), c4 = i % (BK / 4);
            float4 v = *(const float4*)(B + (size_t)(n0 + r) * K + k0 + c4 * 4);
            Bs[r][c4 * 4 + 0] = v.x; Bs[r][c4 * 4 + 1] = v.y;
            Bs[r][c4 * 4 + 2] = v.z; Bs[r][c4 * 4 + 3] = v.w;
        }
        __syncthreads();
        #pragma unroll
        for (int kk = 0; kk < BK; ++kk) {
            float a[TM], b[4];
            #pragma unroll
            for (int i = 0; i < TM; ++i) a[i] = As[ty * TM + i][kk];
            #pragma unroll
            for (int j = 0; j < 4; ++j) b[j] = Bs[tx * 4 + j][kk];
            #pragma unroll
            for (int i = 0; i < TM; ++i)
                #pragma unroll
                for (int j = 0; j < 4; ++j) acc[i][j] += a[i] * b[j];
        }
        __syncthreads();
    }

    #pragma unroll
    for (int j = 0; j < 4; ++j) {
        float bv = bias1 ? bias1[n0 + tx * 4 + j] : 0.f;
        #pragma unroll
        for (int i = 0; i < TM; ++i) acc[i][j] += bv;
    }
    #pragma unroll
    for (int i = 0; i < TM; ++i) {
        int m = m0 + ty * TM + i;
        float4 v = make_float4(acc[i][0], acc[i][1], acc[i][2], acc[i][3]);
        *(float4*)(C + (size_t)m * N + n0 + tx * 4) = v;
    }
}

// ---------------------------------------------------------------------------
__global__ void unpack_h(const u64* __restrict__ hp, float* __restrict__ out,
                         int n) {
    int i = blockIdx.x * blockDim.x + threadIdx.x;
    if (i < n) out[i] = __uint_as_float((unsigned)hp[i]);
}

// ---------------------------------------------------------------------------
// 32 WGs/layer x 1024 thr (16 waves). Lane = row (gate*16 + col_local).
// Layers 1/2: wave wv owns k-chunk [wv*64,+64) of concat [prev-h; own-h]:
//   wv<8 -> prev-h / Wih, wv>=8 -> own-h / Whh. Lane polls one element into
//   a VGPR; dot = 64x readlane-broadcast + fmac against w[64].
// Layer 0: wave wv owns own-h k [wv*32,+32) (lanes 0-31 poll) AND x k
//   [2wv, 2wv+1] (lanes 32-33 load seq; weights in w[32..33]) — balanced
//   across all 16 waves so L0 is strictly the fastest layer (lead cascade).
// ---------------------------------------------------------------------------
__global__ __launch_bounds__(NTH, 4)
void lstm_fused(const float* __restrict__ seq,
                const float* __restrict__ Wih1, const float* __restrict__ Whh1,
                const float* __restrict__ bih1, const float* __restrict__ bhh1,
                const float* __restrict__ Wih2, const float* __restrict__ Whh2,
                const float* __restrict__ bih2, const float* __restrict__ bhh2,
                const float* __restrict__ Wih3, const float* __restrict__ Whh3,
                const float* __restrict__ bih3, const float* __restrict__ bhh3,
                u64* __restrict__ hp) {
    __shared__ float part[2][NTH];      // [pb][wv*64 + row]

    const int blk   = blockIdx.x;
    const int layer = blk >> 5;
    const int g     = blk & 31;
    const int tid   = threadIdx.x;
    const int wv    = tid >> 6;          // 0..15
    const int lane  = tid & 63;          // = row (gate*16 + col_local)
    const int grow  = (lane >> 4) * HDIM + g * 16 + (lane & 15);

    const float* Wih = layer == 0 ? Wih1 : (layer == 1 ? Wih2 : Wih3);
    const float* Whh = layer == 0 ? Whh1 : (layer == 1 ? Whh2 : Whh3);
    const float* bih = layer == 0 ? bih1 : (layer == 1 ? bih2 : bih3);
    const float* bhh = layer == 0 ? bhh1 : (layer == 1 ? bhh2 : bhh3);

    // ---- 64 weight floats/lane (loop-constant indexing only) ----
    float w[64];
    #pragma unroll
    for (int m = 0; m < 64; ++m) w[m] = 0.f;
    if (layer == 0) {
        const float* wp = Whh + (size_t)grow * HDIM + wv * 32;
        #pragma unroll
        for (int i = 0; i < 8; ++i) {
            float4 v = ((const float4*)wp)[i];
            w[4*i+0]=v.x; w[4*i+1]=v.y; w[4*i+2]=v.z; w[4*i+3]=v.w;
        }
        // x weights: 2 per wave (k = 2wv, 2wv+1), all 16 waves balanced.
        w[32] = Wih[(size_t)grow * 32 + 2 * wv + 0];
        w[33] = Wih[(size_t)grow * 32 + 2 * wv + 1];
    } else {
        const float* wp = (wv < 8)
            ? Wih + (size_t)grow * HDIM + wv * 64
            : Whh + (size_t)grow * HDIM + (wv - 8) * 64;
        #pragma unroll
        for (int i = 0; i < 16; ++i) {
            float4 v = ((const float4*)wp)[i];
            w[4*i+0]=v.x; w[4*i+1]=v.y; w[4*i+2]=v.z; w[4*i+3]=v.w;
        }
    }
    #pragma unroll
    for (int m = 0; m < 64; ++m) asm volatile("" : "+v"(w[m]));

    const float brow = bih[grow] + bhh[grow];

    u64*       hpOwn  = hp + (size_t)layer * T_SEQ * HDIM;
    const u64* hpPrev = hp + (size_t)(layer > 0 ? layer - 1 : 0) * T_SEQ * HDIM;

    float c = 0.f;   // cell state (wave 0, lanes 0..15)

    for (unsigned t = 0; t < T_SEQ; ++t) {
        const int pb = t & 1;

        // ---- per-wave poll: chunk element straight into a VGPR ----
        float hval = 0.f;
        float xval = 0.f;
        if (layer == 0) {
            if (lane < 32 && t > 0) {
                const u64* ph = hpOwn + (size_t)(t - 1) * HDIM + wv * 32 + lane;
                u64 v;
                do { v = cohLoad(ph); } while ((unsigned)(v >> 32) != t);
                hval = __uint_as_float((unsigned)v);
            }
            if (lane >= 32 && lane < 34)     // x: 2 elements per wave
                xval = seq[(size_t)t * 32 + 2 * wv + (lane - 32)];
        } else {
            if (wv < 8) {                        // prev-layer h[t], tag t+1
                const u64* px = hpPrev + (size_t)t * HDIM + wv * 64 + lane;
                u64 v;
                do { v = cohLoad(px); } while ((unsigned)(v >> 32) != t + 1u);
                hval = __uint_as_float((unsigned)v);
            } else if (t > 0) {                  // own h[t-1], tag t
                const u64* ph = hpOwn + (size_t)(t - 1) * HDIM
                              + (wv - 8) * 64 + lane;
                u64 v;
                do { v = cohLoad(ph); } while ((unsigned)(v >> 32) != t);
                hval = __uint_as_float((unsigned)v);
            }
        }

        // ---- dot: readlane broadcast + fmac, NO LDS ----
        float pe = 0.f, po = 0.f;
        if (layer == 0) {
            #pragma unroll
            for (int k = 0; k < 32; k += 2) {
                pe = fmaf(bcast(hval, k),     w[k],     pe);
                po = fmaf(bcast(hval, k + 1), w[k + 1], po);
            }
            // balanced x contribution: 2 MACs per wave
            pe = fmaf(bcast(xval, 32), w[32], pe);
            po = fmaf(bcast(xval, 33), w[33], po);
        } else {
            #pragma unroll
            for (int k = 0; k < 64; k += 2) {
                pe = fmaf(bcast(hval, k),     w[k],     pe);
                po = fmaf(bcast(hval, k + 1), w[k + 1], po);
            }
        }
        part[pb][wv * 64 + lane] = pe + po;
        __syncthreads();

        // ---- wave 0: cross-wave sum, gates, ONE coalesced 128B publish ----
        if (wv == 0) {
            float tot = brow;
            #pragma unroll
            for (int wvv = 0; wvv < 16; ++wvv) tot += part[pb][wvv * 64 + lane];
            const int c16 = lane & 15;
            float ai = __shfl(tot, c16 +  0, 64);
            float af = __shfl(tot, c16 + 16, 64);
            float ag = __shfl(tot, c16 + 32, 64);
            float ao = __shfl(tot, c16 + 48, 64);
            if (lane < 16) {
                float iv = fsigmoid(ai);
                float fv = fsigmoid(af);
                float gv = ftanh(ag);
                float ov = fsigmoid(ao);
                c = fv * c + iv * gv;
                float h = ov * ftanh(c);
                u64 pkt = (u64)__float_as_uint(h) | ((u64)(t + 1u) << 32);
                cohStore(hpOwn + (size_t)t * HDIM + g * 16 + lane, pkt);
            }
        }
        // Other waves roll straight into polling t+1 (no pre-dot barrier:
        // each wave consumes only its own polled registers). part[] is
        // double-buffered; writes to part[pb] recur only at t+2, after
        // barrier(t+1), which wave 0 reaches only after its tail(t) reads.
    }
}

// ---------------------------------------------------------------------------
extern "C" void kernel_launch(void* const* d_in, const int* in_sizes, int n_in,
                              void* d_out, int out_size, void* d_ws, size_t ws_size,
                              hipStream_t stream) {
    const float* seq   = (const float*)d_in[0];
    const float* W_ih1 = (const float*)d_in[1];
    const float* W_hh1 = (const float*)d_in[2];
    const float* b_ih1 = (const float*)d_in[3];
    const float* b_hh1 = (const float*)d_in[4];
    const float* W_ih2 = (const float*)d_in[5];
    const float* W_hh2 = (const float*)d_in[6];
    const float* b_ih2 = (const float*)d_in[7];
    const float* b_hh2 = (const float*)d_in[8];
    const float* W_ih3 = (const float*)d_in[9];
    const float* W_hh3 = (const float*)d_in[10];
    const float* b_ih3 = (const float*)d_in[11];
    const float* b_hh3 = (const float*)d_in[12];
    const float* W_out = (const float*)d_in[13];
    const float* b_out = (const float*)d_in[14];
    float* out = (float*)d_out;

    // Workspace: hp[3][T][512] packed u64 (50.3MB); hs2 floats reuse the
    // dead layer-0 packed region after the recurrence.
    u64*   hp   = (u64*)d_ws;
    float* hs2f = (float*)d_ws;
    const u64* hp2 = hp + (size_t)2 * T_SEQ * HDIM;

    hipMemsetAsync(hp, 0, (size_t)3 * T_SEQ * HDIM * sizeof(u64), stream);

    lstm_fused<<<3 * NWG_L, NTH, 0, stream>>>(
        seq, W_ih1, W_hh1, b_ih1, b_hh1, W_ih2, W_hh2, b_ih2, b_hh2,
        W_ih3, W_hh3, b_ih3, b_hh3, hp);

    const int n = T_SEQ * HDIM;
    unpack_h<<<(n + 255) / 256, 256, 0, stream>>>(hp2, hs2f, n);

    gemm_abt<64, 32, 32><<<dim3(1, T_SEQ / 64), 256, 0, stream>>>(
        hs2f, W_out, b_out, out, T_SEQ, 32, HDIM);
}

// Round 4
// 6163.675 us; speedup vs baseline: 1.5366x; 1.0172x over previous
//
#include <hip/hip_runtime.h>

// LSTM T=4096, IN=32, H=512, OUT=32, 3 layers + projection.
// R17 = R16 + dual-copy publish (reader fan-out split 64 -> 32 per line).
//   R16 post-mortem: L0 balance neutral -> inter-layer lead is not a lever;
//   the binding loop is the intra-layer own-h cycle.
//   R17 theory: each h-line is polled by ~64 reader-waves (own + next-layer
//   prev), each sampling every ~RTT (~600cy) => ~1 same-line MALL load per
//   9 cyc = service-rate saturation; queueing inflates observe latency by
//   the ~700-1200cy gap between model (~2600) and measured (3640) step.
//   R12 (denser polls regressed) is independent evidence of saturation.
//   R14 bundled this mechanism with 8x volume + 8x redundant publish and
//   was volume-dominated; R17 isolates it: wave 0 publishes h(t) TWICE
//   (hp own-copy for own-h pollers, hpX prev-feed copy for next layer's
//   prev pollers; layers 0-1 only). Lanes 0-15 store copy O, lanes 16-31
//   store copy P in the SAME wave => zero added tail latency; publish
//   volume 48 -> 80 MB total (trivial). Gates computed redundantly on
//   lanes 0-31 (c replicated, bitwise deterministic).
// Protocol invariants (R3-R16):
//   - packed u64 {seq-tag:32 | value:32}: the flag IS the data;
//   - relaxed agent-scope atomics only, NO cache-wide fences;
//   - <=64 weight floats/lane, loop-constant indexing;
//   - publish = ONE wave per 128B line, full-line stores;
//   - full-history buffers, no slot reuse (no timing assumptions);
//   - per-wave poll straight into VGPRs, readlane-broadcast dot;
//   - ONE s_barrier per step, part[] double-buffered;
//   - partial reduction = wave-0 LDS reads (R11/R15: alternatives lose).

#define T_SEQ 4096
#define HDIM  512
#define NWG_L 32
#define NTH   1024

typedef unsigned long long u64;

__device__ __forceinline__ u64 cohLoad(const u64* p) {
    return __hip_atomic_load(p, __ATOMIC_RELAXED, __HIP_MEMORY_SCOPE_AGENT);
}
__device__ __forceinline__ void cohStore(u64* p, u64 v) {
    __hip_atomic_store(p, v, __ATOMIC_RELAXED, __HIP_MEMORY_SCOPE_AGENT);
}
__device__ __forceinline__ float fsigmoid(float x) {
    return __builtin_amdgcn_rcpf(1.f + __expf(-x));
}
__device__ __forceinline__ float ftanh(float x) {
    float e = __expf(2.f * fabsf(x));           // +inf ok -> t = 1
    float t = 1.f - 2.f * __builtin_amdgcn_rcpf(e + 1.f);
    return copysignf(t, x);
}
__device__ __forceinline__ float bcast(float v, int k) {
    return __uint_as_float(__builtin_amdgcn_readlane(__float_as_uint(v), k));
}

// ---------------------------------------------------------------------------
// Tiled fp32 GEMM (final projection): C[M][N] = A[M][K] * B[N][K]^T + bias[n]
// ---------------------------------------------------------------------------
template <int BM, int BN, int BK>
__global__ __launch_bounds__(256)
void gemm_abt(const float* __restrict__ A, const float* __restrict__ B,
              const float* __restrict__ bias1,
              float* __restrict__ C, int M, int N, int K) {
    constexpr int NTX = BN / 4;
    constexpr int NTY = 256 / NTX;
    constexpr int TM  = BM / NTY;
    __shared__ float As[BM][BK + 1];
    __shared__ float Bs[BN][BK + 1];

    const int tid = threadIdx.x;
    const int tx = tid % NTX;
    const int ty = tid / NTX;
    const int m0 = blockIdx.y * BM;
    const int n0 = blockIdx.x * BN;

    float acc[TM][4];
    #pragma unroll
    for (int i = 0; i < TM; ++i)
        #pragma unroll
        for (int j = 0; j < 4; ++j) acc[i][j] = 0.f;

    for (int k0 = 0; k0 < K; k0 += BK) {
        constexpr int AV = BM * BK / 4;
        #pragma unroll
        for (int i = tid; i < AV; i += 256) {
            int r = i / (BK / 4), c4 = i % (BK / 4);
            float4 v = *(const float4*)(A + (size_t)(m0 + r) * K + k0 + c4 * 4);
            As[r][c4 * 4 + 0] = v.x; As[r][c4 * 4 + 1] = v.y;
            As[r][c4 * 4 + 2] = v.z; As[r][c4 * 4 + 3] = v.w;
        }
        constexpr int BV = BN * BK / 4;
        #pragma unroll
        for (int i = tid; i < BV; i += 256) {
            int r = i / (BK / 4), c4 = i % (BK / 4);
            float4 v = *(const float4*)(B + (size_t)(n0 + r) * K + k0 + c4 * 4);
            Bs[r][c4 * 4 + 0] = v.x; Bs[r][c4 * 4 + 1] = v.y;
            Bs[r][c4 * 4 + 2] = v.z; Bs[r][c4 * 4 + 3] = v.w;
        }
        __syncthreads();
        #pragma unroll
        for (int kk = 0; kk < BK; ++kk) {
            float a[TM], b[4];
            #pragma unroll
            for (int i = 0; i < TM; ++i) a[i] = As[ty * TM + i][kk];
            #pragma unroll
            for (int j = 0; j < 4; ++j) b[j] = Bs[tx * 4 + j][kk];
            #pragma unroll
            for (int i = 0; i < TM; ++i)
                #pragma unroll
                for (int j = 0; j < 4; ++j) acc[i][j] += a[i] * b[j];
        }
        __syncthreads();
    }

    #pragma unroll
    for (int j = 0; j < 4; ++j) {
        float bv = bias1 ? bias1[n0 + tx * 4 + j] : 0.f;
        #pragma unroll
        for (int i = 0; i < TM; ++i) acc[i][j] += bv;
    }
    #pragma unroll
    for (int i = 0; i < TM; ++i) {
        int m = m0 + ty * TM + i;
        float4 v = make_float4(acc[i][0], acc[i][1], acc[i][2], acc[i][3]);
        *(float4*)(C + (size_t)m * N + n0 + tx * 4) = v;
    }
}

// ---------------------------------------------------------------------------
__global__ void unpack_h(const u64* __restrict__ hp, float* __restrict__ out,
                         int n) {
    int i = blockIdx.x * blockDim.x + threadIdx.x;
    if (i < n) out[i] = __uint_as_float((unsigned)hp[i]);
}

// ---------------------------------------------------------------------------
// 32 WGs/layer x 1024 thr (16 waves). Lane = row (gate*16 + col_local).
// Layers 1/2: wave wv owns k-chunk [wv*64,+64) of concat [prev-h; own-h]:
//   wv<8 -> prev-h / Wih (polled from hpX prev-feed copy),
//   wv>=8 -> own-h / Whh (polled from hp own-copy). Lane polls one element
//   into a VGPR; dot = 64x readlane-broadcast + fmac against w[64].
// Layer 0: wave wv owns own-h k [wv*32,+32) (lanes 0-31 poll own-copy) and
//   x k [2wv,2wv+1] (lanes 32-33 load seq; weights in w[32..33]).
// Publish: wave 0 lanes 0-31 compute gates redundantly (c replicated);
//   lanes 0-15 store the own-copy line, lanes 16-31 store the prev-feed
//   line (layers 0-1) — two 128B lines, one wave, same issue slot.
// ---------------------------------------------------------------------------
__global__ __launch_bounds__(NTH, 4)
void lstm_fused(const float* __restrict__ seq,
                const float* __restrict__ Wih1, const float* __restrict__ Whh1,
                const float* __restrict__ bih1, const float* __restrict__ bhh1,
                const float* __restrict__ Wih2, const float* __restrict__ Whh2,
                const float* __restrict__ bih2, const float* __restrict__ bhh2,
                const float* __restrict__ Wih3, const float* __restrict__ Whh3,
                const float* __restrict__ bih3, const float* __restrict__ bhh3,
                u64* __restrict__ hp) {
    __shared__ float part[2][NTH];      // [pb][wv*64 + row]

    const int blk   = blockIdx.x;
    const int layer = blk >> 5;
    const int g     = blk & 31;
    const int tid   = threadIdx.x;
    const int wv    = tid >> 6;          // 0..15
    const int lane  = tid & 63;          // = row (gate*16 + col_local)
    const int grow  = (lane >> 4) * HDIM + g * 16 + (lane & 15);

    const float* Wih = layer == 0 ? Wih1 : (layer == 1 ? Wih2 : Wih3);
    const float* Whh = layer == 0 ? Whh1 : (layer == 1 ? Whh2 : Whh3);
    const float* bih = layer == 0 ? bih1 : (layer == 1 ? bih2 : bih3);
    const float* bhh = layer == 0 ? bhh1 : (layer == 1 ? bhh2 : bhh3);

    // ---- 64 weight floats/lane (loop-constant indexing only) ----
    float w[64];
    #pragma unroll
    for (int m = 0; m < 64; ++m) w[m] = 0.f;
    if (layer == 0) {
        const float* wp = Whh + (size_t)grow * HDIM + wv * 32;
        #pragma unroll
        for (int i = 0; i < 8; ++i) {
            float4 v = ((const float4*)wp)[i];
            w[4*i+0]=v.x; w[4*i+1]=v.y; w[4*i+2]=v.z; w[4*i+3]=v.w;
        }
        // x weights: 2 per wave (k = 2wv, 2wv+1), all 16 waves balanced.
        w[32] = Wih[(size_t)grow * 32 + 2 * wv + 0];
        w[33] = Wih[(size_t)grow * 32 + 2 * wv + 1];
    } else {
        const float* wp = (wv < 8)
            ? Wih + (size_t)grow * HDIM + wv * 64
            : Whh + (size_t)grow * HDIM + (wv - 8) * 64;
        #pragma unroll
        for (int i = 0; i < 16; ++i) {
            float4 v = ((const float4*)wp)[i];
            w[4*i+0]=v.x; w[4*i+1]=v.y; w[4*i+2]=v.z; w[4*i+3]=v.w;
        }
    }
    #pragma unroll
    for (int m = 0; m < 64; ++m) asm volatile("" : "+v"(w[m]));

    const float brow = bih[grow] + bhh[grow];

    // hp layout: [0..3) own-copies per layer; [3..5) prev-feed copies (L0,L1).
    u64*       hpOwn   = hp + (size_t)layer * T_SEQ * HDIM;
    u64*       hpX     = hp + (size_t)3 * T_SEQ * HDIM;
    u64*       hpXOwn  = hpX + (size_t)layer * T_SEQ * HDIM;        // L0/L1
    const u64* hpPrevX = hpX + (size_t)(layer > 0 ? layer - 1 : 0) * T_SEQ * HDIM;

    float c = 0.f;   // cell state (wave 0, lanes 0..31, replicated 16/16)

    for (unsigned t = 0; t < T_SEQ; ++t) {
        const int pb = t & 1;

        // ---- per-wave poll: chunk element straight into a VGPR ----
        float hval = 0.f;
        float xval = 0.f;
        if (layer == 0) {
            if (lane < 32 && t > 0) {
                const u64* ph = hpOwn + (size_t)(t - 1) * HDIM + wv * 32 + lane;
                u64 v;
                do { v = cohLoad(ph); } while ((unsigned)(v >> 32) != t);
                hval = __uint_as_float((unsigned)v);
            }
            if (lane >= 32 && lane < 34)     // x: 2 elements per wave
                xval = seq[(size_t)t * 32 + 2 * wv + (lane - 32)];
        } else {
            if (wv < 8) {              // prev-layer h[t] via prev-feed copy
                const u64* px = hpPrevX + (size_t)t * HDIM + wv * 64 + lane;
                u64 v;
                do { v = cohLoad(px); } while ((unsigned)(v >> 32) != t + 1u);
                hval = __uint_as_float((unsigned)v);
            } else if (t > 0) {        // own h[t-1] via own-copy, tag t
                const u64* ph = hpOwn + (size_t)(t - 1) * HDIM
                              + (wv - 8) * 64 + lane;
                u64 v;
                do { v = cohLoad(ph); } while ((unsigned)(v >> 32) != t);
                hval = __uint_as_float((unsigned)v);
            }
        }

        // ---- dot: readlane broadcast + fmac, NO LDS ----
        float pe = 0.f, po = 0.f;
        if (layer == 0) {
            #pragma unroll
            for (int k = 0; k < 32; k += 2) {
                pe = fmaf(bcast(hval, k),     w[k],     pe);
                po = fmaf(bcast(hval, k + 1), w[k + 1], po);
            }
            // balanced x contribution: 2 MACs per wave
            pe = fmaf(bcast(xval, 32), w[32], pe);
            po = fmaf(bcast(xval, 33), w[33], po);
        } else {
            #pragma unroll
            for (int k = 0; k < 64; k += 2) {
                pe = fmaf(bcast(hval, k),     w[k],     pe);
                po = fmaf(bcast(hval, k + 1), w[k + 1], po);
            }
        }
        part[pb][wv * 64 + lane] = pe + po;
        __syncthreads();

        // ---- wave 0: cross-wave sum, gates, dual-copy 128B publishes ----
        if (wv == 0) {
            float tot = brow;
            #pragma unroll
            for (int wvv = 0; wvv < 16; ++wvv) tot += part[pb][wvv * 64 + lane];
            const int c16 = lane & 15;
            float ai = __shfl(tot, c16 +  0, 64);
            float af = __shfl(tot, c16 + 16, 64);
            float ag = __shfl(tot, c16 + 32, 64);
            float ao = __shfl(tot, c16 + 48, 64);
            if (lane < 32) {
                float iv = fsigmoid(ai);
                float fv = fsigmoid(af);
                float gv = ftanh(ag);
                float ov = fsigmoid(ao);
                c = fv * c + iv * gv;        // replicated lanes 0-15 / 16-31
                float h = ov * ftanh(c);
                u64 pkt = (u64)__float_as_uint(h) | ((u64)(t + 1u) << 32);
                if (lane < 16)               // own-copy: own-h pollers only
                    cohStore(hpOwn + (size_t)t * HDIM + g * 16 + lane, pkt);
                else if (layer < 2)          // prev-feed copy: next layer only
                    cohStore(hpXOwn + (size_t)t * HDIM + g * 16 + (lane - 16),
                             pkt);
            }
        }
        // Other waves roll straight into polling t+1 (no pre-dot barrier:
        // each wave consumes only its own polled registers). part[] is
        // double-buffered; writes to part[pb] recur only at t+2, after
        // barrier(t+1), which wave 0 reaches only after its tail(t) reads.
    }
}

// ---------------------------------------------------------------------------
extern "C" void kernel_launch(void* const* d_in, const int* in_sizes, int n_in,
                              void* d_out, int out_size, void* d_ws, size_t ws_size,
                              hipStream_t stream) {
    const float* seq   = (const float*)d_in[0];
    const float* W_ih1 = (const float*)d_in[1];
    const float* W_hh1 = (const float*)d_in[2];
    const float* b_ih1 = (const float*)d_in[3];
    const float* b_hh1 = (const float*)d_in[4];
    const float* W_ih2 = (const float*)d_in[5];
    const float* W_hh2 = (const float*)d_in[6];
    const float* b_ih2 = (const float*)d_in[7];
    const float* b_hh2 = (const float*)d_in[8];
    const float* W_ih3 = (const float*)d_in[9];
    const float* W_hh3 = (const float*)d_in[10];
    const float* b_ih3 = (const float*)d_in[11];
    const float* b_hh3 = (const float*)d_in[12];
    const float* W_out = (const float*)d_in[13];
    const float* b_out = (const float*)d_in[14];
    float* out = (float*)d_out;

    // Workspace: hp[3][T][512] own-copies (50.3MB) + hpX[2][T][512]
    // prev-feed copies (33.5MB); hs2 floats reuse the dead layer-0
    // packed region after the recurrence.
    u64*   hp   = (u64*)d_ws;
    float* hs2f = (float*)d_ws;
    const u64* hp2 = hp + (size_t)2 * T_SEQ * HDIM;

    hipMemsetAsync(hp, 0, (size_t)5 * T_SEQ * HDIM * sizeof(u64), stream);

    lstm_fused<<<3 * NWG_L, NTH, 0, stream>>>(
        seq, W_ih1, W_hh1, b_ih1, b_hh1, W_ih2, W_hh2, b_ih2, b_hh2,
        W_ih3, W_hh3, b_ih3, b_hh3, hp);

    const int n = T_SEQ * HDIM;
    unpack_h<<<(n + 255) / 256, 256, 0, stream>>>(hp2, hs2f, n);

    gemm_abt<64, 32, 32><<<dim3(1, T_SEQ / 64), 256, 0, stream>>>(
        hs2f, W_out, b_out, out, T_SEQ, 32, HDIM);
}